// Round 1
// baseline (2067.453 us; speedup 1.0000x reference)
//
#include <hip/hip_runtime.h>
#include <hip/hip_bf16.h>
#include <math.h>

#define NEG 0.01f

__device__ __forceinline__ float leaky(float x){ return x >= 0.f ? x : NEG*x; }
__device__ __forceinline__ float4 ld4s(const float* p){ return *(const float4*)p; }

// ---------------- CSR build ----------------
__global__ void k_deg(const int* __restrict__ dst, int* __restrict__ deg, int E){
  int e = blockIdx.x*256 + threadIdx.x;
  if (e < E) atomicAdd(&deg[dst[e]], 1);
}

__global__ __launch_bounds__(1024) void k_scan(const int* __restrict__ deg, int* __restrict__ off, int N){
  __shared__ int buf[1024];
  __shared__ int carry_s;
  if (threadIdx.x == 0) carry_s = 0;
  __syncthreads();
  for (int base = 0; base < N; base += 1024){
    int i = base + threadIdx.x;
    int v = (i < N) ? deg[i] : 0;
    buf[threadIdx.x] = v;
    __syncthreads();
    for (int s = 1; s < 1024; s <<= 1){
      int t = (threadIdx.x >= s) ? buf[threadIdx.x - s] : 0;
      __syncthreads();
      buf[threadIdx.x] += t;
      __syncthreads();
    }
    if (i < N) off[i] = carry_s + buf[threadIdx.x] - v;   // exclusive
    int tot = buf[1023];
    __syncthreads();
    if (threadIdx.x == 0) carry_s += tot;
    __syncthreads();
  }
  if (threadIdx.x == 0) off[N] = carry_s;
}

__global__ void k_fill(const int* __restrict__ dst, const int* __restrict__ off,
                       int* __restrict__ cursor, int* __restrict__ eids, int E){
  int e = blockIdx.x*256 + threadIdx.x;
  if (e < E){
    int d = dst[e];
    int p = atomicAdd(&cursor[d], 1);
    eids[off[d] + p] = e;
  }
}

// ---------------- weight transposes: [2,O,I,G] -> [K][O] ----------------
__global__ void k_prep(const float* __restrict__ ek_c, const float* __restrict__ nk_c,
                       const float* __restrict__ on_c, const float* __restrict__ oe_c,
                       float* __restrict__ WE, float* __restrict__ WN,
                       float* __restrict__ WO, float* __restrict__ WOE){
  int tid = blockIdx.x*256 + threadIdx.x;
  if (tid < 32768){                       // WE [256][128], k = t*128+i
    int k = tid >> 7, o = tid & 127;
    int t = k >> 7, i = k & 127;
    WE[tid] = ek_c[((t*128 + o) << 7) + i];
  } else if (tid < 32768 + 73728){        // WN [384][192], k = t*192+i
    int r = tid - 32768;
    int k = r / 192, o = r % 192;
    int t = k / 192, i = k % 192;
    WN[r] = nk_c[(t*192 + o)*192 + i];
  } else if (tid < 32768 + 73728 + 131072){ // WO [1024][128], k = t*512+i*4+g
    int r = tid - (32768 + 73728);
    int k = r >> 7, o = r & 127;
    int t = k >> 9, q = k & 511, i = q >> 2, g = q & 3;
    WO[r] = on_c[(((t*128 + o) << 7) + i)*4 + g];
  } else if (tid < 32768 + 73728 + 131072 + 8192){ // WOE [256][32]
    int r = tid - (32768 + 73728 + 131072);
    int k = r >> 5, o = r & 31;
    int t = k >> 7, q = k & 127, i = q >> 2, g = q & 3;
    WOE[r] = oe_c[((t*32 + o)*32 + i)*4 + g];
  }
}

// ---------------- generic f32 GEMM, 64x64 tile, BK=32 ----------------
// MODE 0: A[r*lda+k]
// MODE 1: trig-G4 features of A=[M,128]: k=t*512+i*4+g -> trig_t(A[r,i]*(g+1)), K=1024
// MODE 2: trig-G1 of concat(A=[M,128], A2=[M,64]): k=t*192+i -> trig_t(x_i), K=384
template<int MODE>
__global__ __launch_bounds__(256) void k_gemm(const float* __restrict__ A, int lda,
        const float* __restrict__ A2,
        const float* __restrict__ B,          // [K][Ncols]
        float* __restrict__ C, int ldc,
        const float* __restrict__ bias,
        int M, int Ncols, int K){
  __shared__ float As[32*68];   // A^T tile [32k][64r] pad->68
  __shared__ float Bs[32*64];
  int r_blk = blockIdx.x*64, c_blk = blockIdx.y*64;
  int tid = threadIdx.x;
  int tx = tid & 15, ty = tid >> 4;
  float acc[4][4] = {};
  for (int k0 = 0; k0 < K; k0 += 32){
    int ka = tid & 31, ra0 = tid >> 5;
    #pragma unroll
    for (int rr = 0; rr < 8; rr++){
      int r = r_blk + ra0 + rr*8;
      int k = k0 + ka;
      float v = 0.f;
      if (r < M){
        if (MODE == 0){
          v = A[(size_t)r*lda + k];
        } else if (MODE == 1){
          int q = k & 511, i = q >> 2, g = (q & 3) + 1;
          float x = A[((size_t)r << 7) + i] * (float)g;
          v = (k < 512) ? __cosf(x) : __sinf(x);
        } else {
          int i = k % 192;
          float x = (i < 128) ? A[((size_t)r << 7) + i] : A2[((size_t)r << 6) + (i - 128)];
          v = (k < 192) ? __cosf(x) : __sinf(x);
        }
      }
      As[ka*68 + ra0 + rr*8] = v;
    }
    int cb = tid & 63, kb0 = tid >> 6;
    #pragma unroll
    for (int kk = 0; kk < 8; kk++){
      int k = kb0 + kk*4;
      Bs[k*64 + cb] = B[(size_t)(k0 + k)*Ncols + c_blk + cb];
    }
    __syncthreads();
    #pragma unroll
    for (int k = 0; k < 32; k++){
      float4 a4 = ld4s(&As[k*68 + (ty << 2)]);
      float4 b4 = ld4s(&Bs[(k << 6) + (tx << 2)]);
      float av[4] = {a4.x, a4.y, a4.z, a4.w};
      float bv[4] = {b4.x, b4.y, b4.z, b4.w};
      #pragma unroll
      for (int i = 0; i < 4; i++)
        #pragma unroll
        for (int j = 0; j < 4; j++)
          acc[i][j] += av[i]*bv[j];
    }
    __syncthreads();
  }
  #pragma unroll
  for (int i = 0; i < 4; i++){
    int r = r_blk + (ty << 2) + i;
    if (r < M){
      int c = c_blk + (tx << 2);
      float4 o4;
      o4.x = acc[i][0] + (bias ? bias[c+0] : 0.f);
      o4.y = acc[i][1] + (bias ? bias[c+1] : 0.f);
      o4.z = acc[i][2] + (bias ? bias[c+2] : 0.f);
      o4.w = acc[i][3] + (bias ? bias[c+3] : 0.f);
      *(float4*)&C[(size_t)r*ldc + c] = o4;
    }
  }
}

// ---------------- fused edge kernel: 32 edges / wg ----------------
__global__ __launch_bounds__(256) void k_edge(
    const float* __restrict__ P,          // [N][256] = [P_ni | P_nj]
    const float* __restrict__ edge_feats, // [E][64]
    const int* __restrict__ src, const int* __restrict__ dst,
    const float* __restrict__ W_fij,      // [64][128]
    const float* __restrict__ WE,         // [256][128]
    const float* __restrict__ ek_b, const float* __restrict__ bias_edge,
    const float* __restrict__ attn,       // [4][32]
    const float* __restrict__ WOE,        // [256][32]
    const float* __restrict__ oe_b,       // [32]
    float* __restrict__ scores,           // [E][4]
    float* __restrict__ out_edge,         // [E][32]
    int E)
{
  __shared__ float cs[32*264];   // cos|sin features -> f tile -> tfeat
  __shared__ float wb[64*128];   // ef tile -> WE chunk -> WOE
  __shared__ float fsum[32*33];
  __shared__ float attn_s[128];
  __shared__ float ekb_s[128];
  __shared__ float oeb_s[32];
  __shared__ int   se[32], de[32];
  int tid = threadIdx.x;
  int e0 = blockIdx.x * 32;

  { // stage ef tile into wb ([32][68]) + misc
    int i = tid & 63, er = tid >> 6;
    #pragma unroll
    for (int q = 0; q < 8; q++){
      int ee = er + q*4;
      wb[ee*68 + i] = edge_feats[(size_t)(e0 + ee)*64 + i];
    }
    if (tid < 128){ attn_s[tid] = attn[tid]; ekb_s[tid] = ek_b[tid] + bias_edge[tid]; }
    if (tid < 32){ oeb_s[tid] = oe_b[tid]; se[tid] = src[e0 + tid]; de[tid] = dst[e0 + tid]; }
  }
  __syncthreads();

  // phase 1: x = P_ni[src] + P_nj[dst] + ef @ W_fij, then trig -> cs
  {
    int c = tid & 127, eh = tid >> 7;
    float x[16];
    #pragma unroll
    for (int e = 0; e < 16; e++){
      int ee = eh*16 + e;
      x[e] = P[(size_t)se[ee]*256 + c] + P[(size_t)de[ee]*256 + 128 + c];
    }
    #pragma unroll
    for (int i0 = 0; i0 < 64; i0 += 4){
      float w0 = W_fij[(i0+0)*128 + c];
      float w1 = W_fij[(i0+1)*128 + c];
      float w2 = W_fij[(i0+2)*128 + c];
      float w3 = W_fij[(i0+3)*128 + c];
      #pragma unroll
      for (int e = 0; e < 16; e++){
        float4 ef4 = ld4s(&wb[(eh*16+e)*68 + i0]);
        x[e] += w0*ef4.x + w1*ef4.y + w2*ef4.z + w3*ef4.w;
      }
    }
    #pragma unroll
    for (int e = 0; e < 16; e++){
      int ee = eh*16 + e;
      cs[ee*264 + c]       = __cosf(x[e]);
      cs[ee*264 + 128 + c] = __sinf(x[e]);
    }
  }
  __syncthreads();

  // phase 3: f = [cos|sin] @ WE  (32x128, K=256), WE chunked through LDS
  int to = tid & 31, te = tid >> 5;
  float facc[4][4] = {};
  for (int k0 = 0; k0 < 256; k0 += 64){
    int o = tid & 127, kk0 = tid >> 7;
    #pragma unroll
    for (int kk = 0; kk < 32; kk++){
      int k = 2*kk + kk0;
      wb[k*128 + o] = WE[(size_t)(k0 + k)*128 + o];
    }
    __syncthreads();
    #pragma unroll
    for (int k = 0; k < 64; k += 4){
      float av[4][4];
      #pragma unroll
      for (int i = 0; i < 4; i++){
        float4 t = ld4s(&cs[(te*4+i)*264 + k0 + k]);
        av[i][0]=t.x; av[i][1]=t.y; av[i][2]=t.z; av[i][3]=t.w;
      }
      #pragma unroll
      for (int j = 0; j < 4; j++){
        float4 b4 = ld4s(&wb[(k+j)*128 + (to << 2)]);
        #pragma unroll
        for (int i = 0; i < 4; i++){
          facc[i][0] += av[i][j]*b4.x;
          facc[i][1] += av[i][j]*b4.y;
          facc[i][2] += av[i][j]*b4.z;
          facc[i][3] += av[i][j]*b4.w;
        }
      }
    }
    __syncthreads();
  }

  // phase 4: leaky(f + ek_b + bias_edge) -> f_lds ([32][132], reuses cs)
  float* f_lds = cs;
  #pragma unroll
  for (int i = 0; i < 4; i++){
    int ee = te*4 + i;
    float4 o4;
    o4.x = leaky(facc[i][0] + ekb_s[(to<<2)+0]);
    o4.y = leaky(facc[i][1] + ekb_s[(to<<2)+1]);
    o4.z = leaky(facc[i][2] + ekb_s[(to<<2)+2]);
    o4.w = leaky(facc[i][3] + ekb_s[(to<<2)+3]);
    *(float4*)&f_lds[ee*132 + (to<<2)] = o4;
  }
  __syncthreads();

  // scores + f_sum
  if (tid < 128){
    int e = tid >> 2, hh = tid & 3;
    float s = 0.f;
    #pragma unroll
    for (int j = 0; j < 32; j++) s += f_lds[e*132 + hh*32 + j] * attn_s[hh*32 + j];
    scores[(size_t)(e0 + e)*4 + hh] = s;
  }
  {
    int e = tid >> 3, jb = tid & 7;
    #pragma unroll
    for (int j2 = 0; j2 < 4; j2++){
      int j = jb*4 + j2;
      fsum[e*33 + j] = f_lds[e*132 + j] + f_lds[e*132 + 32 + j]
                     + f_lds[e*132 + 64 + j] + f_lds[e*132 + 96 + j];
    }
  }
  __syncthreads();

  // phase 5: oe-KAN. stage WOE into wb, tfeat into cs, then GEMM 32x32xK256
  {
    int o = tid & 31, kq0 = tid >> 5;
    #pragma unroll
    for (int kk = 0; kk < 32; kk++){
      int k = kk*8 + kq0;
      wb[k*32 + o] = WOE[k*32 + o];
    }
  }
  {
    int e = tid >> 3, jb = tid & 7;
    #pragma unroll
    for (int j2 = 0; j2 < 4; j2++){
      int j = jb*4 + j2;
      float xv = fsum[e*33 + j];
      #pragma unroll
      for (int g = 1; g <= 4; g++){
        float xg = xv * (float)g;
        cs[e*264 + (j<<2) + (g-1)]       = __cosf(xg);
        cs[e*264 + 128 + (j<<2) + (g-1)] = __sinf(xg);
      }
    }
  }
  __syncthreads();
  {
    int e = tid >> 3, ob = tid & 7;
    float a4[4] = {};
    #pragma unroll
    for (int k = 0; k < 256; k += 4){
      float4 t4 = ld4s(&cs[e*264 + k]);
      float tv[4] = {t4.x, t4.y, t4.z, t4.w};
      #pragma unroll
      for (int j = 0; j < 4; j++){
        float4 w4 = ld4s(&wb[(k+j)*32 + (ob<<2)]);
        a4[0] += tv[j]*w4.x; a4[1] += tv[j]*w4.y; a4[2] += tv[j]*w4.z; a4[3] += tv[j]*w4.w;
      }
    }
    float4 o4;
    o4.x = a4[0] + oeb_s[(ob<<2)+0];
    o4.y = a4[1] + oeb_s[(ob<<2)+1];
    o4.z = a4[2] + oeb_s[(ob<<2)+2];
    o4.w = a4[3] + oeb_s[(ob<<2)+3];
    *(float4*)&out_edge[(size_t)(e0 + e)*32 + (ob<<2)] = o4;
  }
}

// ---------------- per-node stats: softmax max/sum + mean agg ----------------
__global__ __launch_bounds__(256) void k_nodestats(
    const float* __restrict__ edge_feats, const float* __restrict__ scores,
    const int* __restrict__ off, const int* __restrict__ eids,
    float* __restrict__ agg, float* __restrict__ smax, float* __restrict__ rssum, int N)
{
  int n = blockIdx.x*4 + (threadIdx.x >> 6);
  int lane = threadIdx.x & 63;
  if (n >= N) return;
  int s0 = off[n], s1 = off[n+1], d = s1 - s0;
  float acc = 0.f;
  for (int t = s0; t < s1; t++){
    int eid = eids[t];
    acc += edge_feats[(size_t)eid*64 + lane];
  }
  agg[(size_t)n*64 + lane] = acc / (float)max(d, 1);
  if (lane < 4){
    float m = -1e30f;
    for (int t = s0; t < s1; t++) m = fmaxf(m, scores[(size_t)eids[t]*4 + lane]);
    float ss = 0.f;
    for (int t = s0; t < s1; t++) ss += __expf(scores[(size_t)eids[t]*4 + lane] - m);
    smax[n*4 + lane]  = (d > 0) ? m : 0.f;
    rssum[n*4 + lane] = (d > 0) ? 1.f/ss : 0.f;
  }
}

// ---------------- h-aggregation: h_out[n] = sum_h leaky(sum_e a*h[src]) ----------------
__global__ __launch_bounds__(256) void k_aggr(
    const float* __restrict__ h,        // [N][512]
    const float* __restrict__ scores,   // [E][4]
    const int* __restrict__ src,
    const int* __restrict__ off, const int* __restrict__ eids,
    const float* __restrict__ smax, const float* __restrict__ rssum,
    float* __restrict__ h_out, int N)
{
  __shared__ float part[256];
  int n = blockIdx.x;
  int tid = threadIdx.x;
  int ha = tid >> 7;       // 0/1 ; hb = ha+2
  int s0 = off[n], s1 = off[n+1];
  float ma = smax[n*4 + ha],     mb = smax[n*4 + ha + 2];
  float ra = rssum[n*4 + ha],    rb = rssum[n*4 + ha + 2];
  float acc_a = 0.f, acc_b = 0.f;
  for (int t = s0; t < s1; t++){
    int eid = eids[t];
    int sv = src[eid];
    float aa = __expf(scores[(size_t)eid*4 + ha]     - ma) * ra;
    float ab = __expf(scores[(size_t)eid*4 + ha + 2] - mb) * rb;
    acc_a += aa * h[(size_t)sv*512 + tid];
    acc_b += ab * h[(size_t)sv*512 + 256 + tid];
  }
  part[tid] = leaky(acc_a) + leaky(acc_b);
  __syncthreads();
  if (tid < 128) h_out[(size_t)n*128 + tid] = part[tid] + part[tid + 128];
}

extern "C" void kernel_launch(void* const* d_in, const int* in_sizes, int n_in,
                              void* d_out, int out_size, void* d_ws, size_t ws_size,
                              hipStream_t stream){
  const float* node_feats = (const float*)d_in[0];
  const float* edge_feats = (const float*)d_in[1];
  const int*   src        = (const int*)  d_in[2];
  const int*   dst        = (const int*)  d_in[3];
  const float* W_ni       = (const float*)d_in[4];
  const float* W_nj       = (const float*)d_in[5];
  const float* W_fij      = (const float*)d_in[6];
  const float* W_node     = (const float*)d_in[7];
  const float* b_node     = (const float*)d_in[8];
  const float* attn       = (const float*)d_in[9];
  const float* bias_edge  = (const float*)d_in[10];
  const float* ek_c       = (const float*)d_in[11];
  const float* ek_b       = (const float*)d_in[12];
  const float* nk_c       = (const float*)d_in[13];
  const float* nk_b       = (const float*)d_in[14];
  const float* on_c       = (const float*)d_in[15];
  const float* on_b       = (const float*)d_in[16];
  const float* oe_c       = (const float*)d_in[17];
  const float* oe_b       = (const float*)d_in[18];

  const int N = in_sizes[0] / 128;
  const int E = in_sizes[2];

  float* ws = (float*)d_ws;
  size_t o = 0;
  float* P      = ws + o; o += (size_t)N*256;
  float* scores = ws + o; o += (size_t)E*4;
  float* smax   = ws + o; o += (size_t)N*4;
  float* rssum  = ws + o; o += (size_t)N*4;
  float* agg    = ws + o; o += (size_t)N*64;
  float* mk     = ws + o; o += (size_t)N*192;
  float* h      = ws + o; o += (size_t)N*512;
  float* h_out  = ws + o; o += (size_t)N*128;
  float* WE     = ws + o; o += 32768;
  float* WN     = ws + o; o += 73728;
  float* WO     = ws + o; o += 131072;
  float* WOE    = ws + o; o += 8192;
  int* deg    = (int*)(ws + o); o += N;
  int* cursor = (int*)(ws + o); o += N;
  int* off    = (int*)(ws + o); o += (size_t)(N + 1);
  int* eids   = (int*)(ws + o); o += E;

  float* out_node = (float*)d_out;
  float* out_edge = (float*)d_out + (size_t)N*128;

  (void)hipMemsetAsync(deg, 0, sizeof(int)*(size_t)(2*N), stream);   // deg + cursor

  k_deg <<<(E + 255)/256, 256, 0, stream>>>(dst, deg, E);
  k_scan<<<1, 1024, 0, stream>>>(deg, off, N);
  k_fill<<<(E + 255)/256, 256, 0, stream>>>(dst, off, cursor, eids, E);
  k_prep<<<960, 256, 0, stream>>>(ek_c, nk_c, on_c, oe_c, WE, WN, WO, WOE);

  k_gemm<0><<<dim3((N+63)/64, 2), 256, 0, stream>>>(node_feats, 128, nullptr, W_ni,   P,       256, nullptr, N, 128, 128);
  k_gemm<0><<<dim3((N+63)/64, 2), 256, 0, stream>>>(node_feats, 128, nullptr, W_nj,   P + 128, 256, nullptr, N, 128, 128);

  k_edge<<<E/32, 256, 0, stream>>>(P, edge_feats, src, dst, W_fij, WE, ek_b, bias_edge,
                                   attn, WOE, oe_b, scores, out_edge, E);

  k_nodestats<<<(N + 3)/4, 256, 0, stream>>>(edge_feats, scores, off, eids, agg, smax, rssum, N);

  k_gemm<2><<<dim3((N+63)/64, 3), 256, 0, stream>>>(node_feats, 128, agg,     WN,     mk,      192, nk_b,   N, 192, 384);
  k_gemm<0><<<dim3((N+63)/64, 8), 256, 0, stream>>>(mk,         192, nullptr, W_node, h,       512, b_node, N, 512, 192);

  k_aggr<<<N, 256, 0, stream>>>(h, scores, src, off, eids, smax, rssum, h_out, N);

  k_gemm<1><<<dim3((N+63)/64, 2), 256, 0, stream>>>(h_out, 128, nullptr, WO, out_node, 128, on_b, N, 128, 1024);
}

// Round 2
// 1077.444 us; speedup vs baseline: 1.9188x; 1.9188x over previous
//
#include <hip/hip_runtime.h>
#include <hip/hip_bf16.h>
#include <math.h>

#define NEG 0.01f

typedef __attribute__((ext_vector_type(8))) short short8;
typedef __attribute__((ext_vector_type(4))) float f32x4;
typedef unsigned short ushort;

#define MFMA(a,b,c) __builtin_amdgcn_mfma_f32_16x16x32_bf16(a,b,c,0,0,0)

__device__ __forceinline__ float leaky(float x){ return x >= 0.f ? x : NEG*x; }
__device__ __forceinline__ ushort b16(float f){
  unsigned int u = __float_as_uint(f);
  unsigned int r = (u + 0x7FFF + ((u >> 16) & 1)) >> 16;
  return (ushort)r;
}

// ---------------- CSR build ----------------
__global__ void k_deg(const int* __restrict__ dst, int* __restrict__ deg, int E){
  int e = blockIdx.x*256 + threadIdx.x;
  if (e < E) atomicAdd(&deg[dst[e]], 1);
}

__global__ __launch_bounds__(1024) void k_scan(const int* __restrict__ deg, int* __restrict__ off, int N){
  __shared__ int buf[1024];
  __shared__ int carry_s;
  if (threadIdx.x == 0) carry_s = 0;
  __syncthreads();
  for (int base = 0; base < N; base += 1024){
    int i = base + threadIdx.x;
    int v = (i < N) ? deg[i] : 0;
    buf[threadIdx.x] = v;
    __syncthreads();
    for (int s = 1; s < 1024; s <<= 1){
      int t = (threadIdx.x >= s) ? buf[threadIdx.x - s] : 0;
      __syncthreads();
      buf[threadIdx.x] += t;
      __syncthreads();
    }
    if (i < N) off[i] = carry_s + buf[threadIdx.x] - v;   // exclusive
    int tot = buf[1023];
    __syncthreads();
    if (threadIdx.x == 0) carry_s += tot;
    __syncthreads();
  }
  if (threadIdx.x == 0) off[N] = carry_s;
}

__global__ void k_fill(const int* __restrict__ dst, const int* __restrict__ off,
                       int* __restrict__ cursor, int* __restrict__ eids, int E){
  int e = blockIdx.x*256 + threadIdx.x;
  if (e < E){
    int d = dst[e];
    int p = atomicAdd(&cursor[d], 1);
    eids[off[d] + p] = e;
  }
}

// ---------------- weight prep: transpose + bf16, layouts [O][K] k-contiguous ----------------
__global__ void k_prep2(const float* __restrict__ W_ni, const float* __restrict__ W_nj,
                        const float* __restrict__ W_fij, const float* __restrict__ W_node,
                        const float* __restrict__ ek_c, const float* __restrict__ nk_c,
                        const float* __restrict__ on_c, const float* __restrict__ oe_c,
                        ushort* __restrict__ Bni, ushort* __restrict__ Bnj,
                        ushort* __restrict__ Bfij, ushort* __restrict__ BE,
                        ushort* __restrict__ BN_, ushort* __restrict__ BW,
                        ushort* __restrict__ BO, ushort* __restrict__ BOE){
  int t = blockIdx.x*256 + threadIdx.x;
  if (t < 16384){ int o = t >> 7, i = t & 127; Bni[t] = b16(W_ni[i*128 + o]); return; }
  t -= 16384;
  if (t < 16384){ int o = t >> 7, i = t & 127; Bnj[t] = b16(W_nj[i*128 + o]); return; }
  t -= 16384;
  if (t < 8192){ int o = t >> 6, i = t & 63; Bfij[t] = b16(W_fij[i*128 + o]); return; }
  t -= 8192;
  if (t < 32768){ int o = t >> 8, k = t & 255; int tt = k >> 7, i = k & 127;
    BE[t] = b16(ek_c[((tt*128 + o) << 7) + i]); return; }
  t -= 32768;
  if (t < 73728){ int o = t / 384, k = t % 384; int tt = (k >= 192), i = k - tt*192;
    BN_[t] = b16(nk_c[(tt*192 + o)*192 + i]); return; }
  t -= 73728;
  if (t < 98304){ int o = t / 192, i = t % 192; BW[t] = b16(W_node[i*512 + o]); return; }
  t -= 98304;
  if (t < 131072){ int o = t >> 10, k = t & 1023; int tt = k >> 9, q = k & 511, i = q >> 2, g = q & 3;
    BO[t] = b16(on_c[(((tt*128 + o) << 7) + i)*4 + g]); return; }
  t -= 131072;
  if (t < 8192){ int o = t >> 8, k = t & 255; int tt = k >> 7, q = k & 127, i = q >> 2, g = q & 3;
    BOE[t] = b16(oe_c[((tt*32 + o)*32 + i)*4 + g]); return; }
}

// ---------------- dense bf16-MFMA GEMM: 64x64 tile, BK=32, 4 waves ----------------
// MODE 0: A[r*lda + k]  (f32 -> bf16)
// MODE 1: trig-G4 of A=[M,128]: k = t*512 + i*4 + g -> trig_t(A[r,i]*(g+1)), K=1024
// MODE 2: trig-G1 of concat(A=[M,128], A2=[M,64]): k = t*192 + i, K=384
template<int MODE>
__global__ __launch_bounds__(256) void k_mm(
    const float* __restrict__ A, int lda, const float* __restrict__ A2,
    const ushort* __restrict__ B,            // [Ncols][K] bf16 k-contiguous
    float* __restrict__ C, int ldc, const float* __restrict__ bias,
    int M, int K)
{
  __shared__ __align__(16) ushort As[64*40];   // [64 rows][32 k], row pad 40 elems
  const int tid = threadIdx.x;
  const int lane = tid & 63, w = tid >> 6;
  const int l15 = lane & 15, kg = lane >> 4;
  const int r0 = blockIdx.x * 64;
  const int c0 = blockIdx.y * 64;
  const int rg = (w & 1) * 2;
  const int cgb = (w >> 1) * 2;
  f32x4 acc[2][2] = {};
  const int srow = tid >> 2;
  const int kk = (tid & 3) * 8;

  for (int k0 = 0; k0 < K; k0 += 32){
    { // stage A tile (featurized)
      int row = r0 + srow;
      ushort v[8];
      if (MODE == 0){
        if (row < M){
          const float* p = A + (size_t)row*lda + k0 + kk;
          float4 a = *(const float4*)p, b = *(const float4*)(p+4);
          v[0]=b16(a.x); v[1]=b16(a.y); v[2]=b16(a.z); v[3]=b16(a.w);
          v[4]=b16(b.x); v[5]=b16(b.y); v[6]=b16(b.z); v[7]=b16(b.w);
        } else { for (int j=0;j<8;j++) v[j]=0; }
      } else if (MODE == 1){
        int k = k0 + kk;
        int tt = k >> 9, i = (k & 511) >> 2;
        float x0 = 0.f, x1 = 0.f;
        if (row < M){ x0 = A[(size_t)row*128 + i]; x1 = A[(size_t)row*128 + i + 1]; }
        #pragma unroll
        for (int g = 1; g <= 4; g++){
          v[g-1]   = b16(tt ? __sinf(x0*(float)g) : __cosf(x0*(float)g));
          v[3+g]   = b16(tt ? __sinf(x1*(float)g) : __cosf(x1*(float)g));
        }
      } else {
        int k = k0 + kk;
        int tt = (k >= 192), i = k - tt*192;
        float xv8[8] = {0,0,0,0,0,0,0,0};
        if (row < M){
          const float* sp = (i < 128) ? (A + (size_t)row*128 + i) : (A2 + (size_t)row*64 + (i - 128));
          float4 a = *(const float4*)sp, b = *(const float4*)(sp+4);
          xv8[0]=a.x; xv8[1]=a.y; xv8[2]=a.z; xv8[3]=a.w;
          xv8[4]=b.x; xv8[5]=b.y; xv8[6]=b.z; xv8[7]=b.w;
        }
        #pragma unroll
        for (int j = 0; j < 8; j++)
          v[j] = b16(tt ? __sinf(xv8[j]) : __cosf(xv8[j]));
      }
      *(short8*)&As[srow*40 + kk] = *(short8*)v;
    }
    __syncthreads();
    short8 afr[2], bfr[2];
    #pragma unroll
    for (int q = 0; q < 2; q++)
      afr[q] = *(const short8*)&As[((rg+q)*16 + l15)*40 + kg*8];
    #pragma unroll
    for (int q = 0; q < 2; q++)
      bfr[q] = *(const short8*)(B + (size_t)(c0 + (cgb+q)*16 + l15)*K + k0 + kg*8);
    #pragma unroll
    for (int i = 0; i < 2; i++)
      #pragma unroll
      for (int j = 0; j < 2; j++)
        acc[i][j] = MFMA(afr[i], bfr[j], acc[i][j]);
    __syncthreads();
  }
  #pragma unroll
  for (int i = 0; i < 2; i++){
    #pragma unroll
    for (int j = 0; j < 2; j++){
      int col = c0 + (cgb+j)*16 + l15;
      float bv = bias ? bias[col] : 0.f;
      #pragma unroll
      for (int r = 0; r < 4; r++){
        int row = r0 + (rg+i)*16 + kg*4 + r;
        if (row < M) C[(size_t)row*ldc + col] = acc[i][j][r] + bv;
      }
    }
  }
}

// ---------------- fused edge kernel (MFMA): 32 edges / block, 4 waves ----------------
__global__ __launch_bounds__(256) void k_edge(
    const float* __restrict__ P,          // [N][256] = [P_ni | P_nj]
    const float* __restrict__ ef,         // [E][64]
    const int* __restrict__ src, const int* __restrict__ dst,
    const ushort* __restrict__ Bfij,      // [128][64]
    const ushort* __restrict__ BE,        // [128][256]
    const ushort* __restrict__ BOE,       // [32][256]
    const float* __restrict__ ek_b, const float* __restrict__ bias_edge,
    const float* __restrict__ attn, const float* __restrict__ oe_b,
    float* __restrict__ scores,           // [E][4]
    float* __restrict__ out_edge,         // [E][32]
    int E)
{
  __shared__ __align__(16) ushort cs[32*264];  // [32][256+8] bf16 feats; overlaid f32 [32][132]
  __shared__ float fsum[32*33];
  __shared__ float attn_s[128], ekb_s[128], oeb_s[32];
  __shared__ int se[32], de[32];
  const int tid = threadIdx.x;
  const int lane = tid & 63, w = tid >> 6;
  const int l15 = lane & 15, kg = lane >> 4;
  const int e0 = blockIdx.x << 5;

  if (tid < 128){ attn_s[tid] = attn[tid]; ekb_s[tid] = ek_b[tid] + bias_edge[tid]; }
  if (tid < 32){ oeb_s[tid] = oe_b[tid]; se[tid] = src[e0+tid]; de[tid] = dst[e0+tid]; }
  __syncthreads();

  const int eg = w & 1, cq = w >> 1;   // wave: edge-group (16 edges), col-quad (4x16 cols)

  // ---- phase 1: x = ef @ Bfij + P_ni[src] + P_nj[dst]
  short8 afe[2];
  #pragma unroll
  for (int ks = 0; ks < 2; ks++){
    const float* p = ef + (size_t)(e0 + eg*16 + l15)*64 + ks*32 + kg*8;
    float4 u0 = *(const float4*)p, u1 = *(const float4*)(p+4);
    ushort tv[8] = {b16(u0.x),b16(u0.y),b16(u0.z),b16(u0.w),b16(u1.x),b16(u1.y),b16(u1.z),b16(u1.w)};
    afe[ks] = *(short8*)tv;
  }
  float xv[4][4];
  #pragma unroll
  for (int cg = 0; cg < 4; cg++){
    int c = (cq*4 + cg)*16;
    f32x4 acc = {0.f,0.f,0.f,0.f};
    #pragma unroll
    for (int ks = 0; ks < 2; ks++){
      short8 bf = *(const short8*)(Bfij + (size_t)(c + l15)*64 + ks*32 + kg*8);
      acc = MFMA(afe[ks], bf, acc);
    }
    int col = c + l15;
    #pragma unroll
    for (int r = 0; r < 4; r++){
      int e = eg*16 + kg*4 + r;
      xv[cg][r] = acc[r] + P[(size_t)se[e]*256 + col] + P[(size_t)de[e]*256 + 128 + col];
    }
  }
  #pragma unroll
  for (int cg = 0; cg < 4; cg++){
    int col = (cq*4 + cg)*16 + l15;
    #pragma unroll
    for (int r = 0; r < 4; r++){
      int e = eg*16 + kg*4 + r;
      cs[e*264 + col]       = b16(__cosf(xv[cg][r]));
      cs[e*264 + 128 + col] = b16(__sinf(xv[cg][r]));
    }
  }
  __syncthreads();

  // ---- phase 3: f = feats @ BE  ([32][256] x [256][128])
  short8 af[8];
  #pragma unroll
  for (int ks = 0; ks < 8; ks++)
    af[ks] = *(const short8*)&cs[(eg*16 + l15)*264 + ks*32 + kg*8];
  float fv[4][4];
  #pragma unroll
  for (int cg = 0; cg < 4; cg++){
    int c = (cq*4 + cg)*16;
    f32x4 acc = {0.f,0.f,0.f,0.f};
    #pragma unroll
    for (int ks = 0; ks < 8; ks++){
      short8 bf = *(const short8*)(BE + (size_t)(c + l15)*256 + ks*32 + kg*8);
      acc = MFMA(af[ks], bf, acc);
    }
    int col = c + l15;
    #pragma unroll
    for (int r = 0; r < 4; r++)
      fv[cg][r] = leaky(acc[r] + ekb_s[col]);
  }
  __syncthreads();             // everyone done reading cs
  float* f_lds = (float*)cs;   // [32][132]
  #pragma unroll
  for (int cg = 0; cg < 4; cg++){
    int col = (cq*4 + cg)*16 + l15;
    #pragma unroll
    for (int r = 0; r < 4; r++)
      f_lds[(eg*16 + kg*4 + r)*132 + col] = fv[cg][r];
  }
  __syncthreads();

  // ---- scores + f_sum
  if (tid < 128){
    int e = tid >> 2, h = tid & 3;
    float s = 0.f;
    #pragma unroll
    for (int j = 0; j < 32; j++) s += f_lds[e*132 + h*32 + j] * attn_s[h*32 + j];
    scores[(size_t)(e0 + e)*4 + h] = s;
  }
  {
    int e = tid >> 3, j0 = (tid & 7)*4;
    #pragma unroll
    for (int j2 = 0; j2 < 4; j2++){
      int j = j0 + j2;
      fsum[e*33 + j] = f_lds[e*132 + j] + f_lds[e*132 + 32 + j]
                     + f_lds[e*132 + 64 + j] + f_lds[e*132 + 96 + j];
    }
  }
  __syncthreads();

  // ---- phase 5 features: k = t*128 + i*4 + g  (overwrite cs)
  {
    int e = tid >> 3, i0 = (tid & 7)*4;
    ushort cb[16], sb[16];
    #pragma unroll
    for (int i2 = 0; i2 < 4; i2++){
      float x = fsum[e*33 + i0 + i2];
      #pragma unroll
      for (int g = 1; g <= 4; g++){
        float xg = x * (float)g;
        cb[i2*4 + g - 1] = b16(__cosf(xg));
        sb[i2*4 + g - 1] = b16(__sinf(xg));
      }
    }
    *(short8*)&cs[e*264 + i0*4]           = ((short8*)cb)[0];
    *(short8*)&cs[e*264 + i0*4 + 8]       = ((short8*)cb)[1];
    *(short8*)&cs[e*264 + 128 + i0*4]     = ((short8*)sb)[0];
    *(short8*)&cs[e*264 + 128 + i0*4 + 8] = ((short8*)sb)[1];
  }
  __syncthreads();

  // ---- phase 5 MFMA: out_edge = feats @ BOE ([32][256] x [256][32])
  {
    int eg5 = w & 1, cg5 = w >> 1;
    f32x4 acc = {0.f,0.f,0.f,0.f};
    #pragma unroll
    for (int ks = 0; ks < 8; ks++){
      short8 a  = *(const short8*)&cs[(eg5*16 + l15)*264 + ks*32 + kg*8];
      short8 bf = *(const short8*)(BOE + (size_t)(cg5*16 + l15)*256 + ks*32 + kg*8);
      acc = MFMA(a, bf, acc);
    }
    int col = cg5*16 + l15;
    #pragma unroll
    for (int r = 0; r < 4; r++){
      int e = eg5*16 + kg*4 + r;
      out_edge[(size_t)(e0 + e)*32 + col] = acc[r] + oeb_s[col];
    }
  }
}

// ---------------- per-node stats: softmax max/sum + mean agg ----------------
__global__ __launch_bounds__(256) void k_nodestats(
    const float* __restrict__ edge_feats, const float* __restrict__ scores,
    const int* __restrict__ off, const int* __restrict__ eids,
    float* __restrict__ agg, float* __restrict__ smax, float* __restrict__ rssum, int N)
{
  int n = blockIdx.x*4 + (threadIdx.x >> 6);
  int lane = threadIdx.x & 63;
  if (n >= N) return;
  int s0 = off[n], s1 = off[n+1], d = s1 - s0;
  float acc = 0.f;
  for (int t = s0; t < s1; t++){
    int eid = eids[t];
    acc += edge_feats[(size_t)eid*64 + lane];
  }
  agg[(size_t)n*64 + lane] = acc / (float)max(d, 1);
  if (lane < 4){
    float m = -1e30f;
    for (int t = s0; t < s1; t++) m = fmaxf(m, scores[(size_t)eids[t]*4 + lane]);
    float ss = 0.f;
    for (int t = s0; t < s1; t++) ss += __expf(scores[(size_t)eids[t]*4 + lane] - m);
    smax[n*4 + lane]  = (d > 0) ? m : 0.f;
    rssum[n*4 + lane] = (d > 0) ? 1.f/ss : 0.f;
  }
}

// ---------------- h-aggregation ----------------
__global__ __launch_bounds__(256) void k_aggr(
    const float* __restrict__ h,        // [N][512]
    const float* __restrict__ scores,   // [E][4]
    const int* __restrict__ src,
    const int* __restrict__ off, const int* __restrict__ eids,
    const float* __restrict__ smax, const float* __restrict__ rssum,
    float* __restrict__ h_out, int N)
{
  __shared__ float part[256];
  int n = blockIdx.x;
  int tid = threadIdx.x;
  int ha = tid >> 7;
  int s0 = off[n], s1 = off[n+1];
  float ma = smax[n*4 + ha],  mb = smax[n*4 + ha + 2];
  float ra = rssum[n*4 + ha], rb = rssum[n*4 + ha + 2];
  float acc_a = 0.f, acc_b = 0.f;
  for (int t = s0; t < s1; t++){
    int eid = eids[t];
    int sv = src[eid];
    float aa = __expf(scores[(size_t)eid*4 + ha]     - ma) * ra;
    float ab = __expf(scores[(size_t)eid*4 + ha + 2] - mb) * rb;
    acc_a += aa * h[(size_t)sv*512 + tid];
    acc_b += ab * h[(size_t)sv*512 + 256 + tid];
  }
  part[tid] = leaky(acc_a) + leaky(acc_b);
  __syncthreads();
  if (tid < 128) h_out[(size_t)n*128 + tid] = part[tid] + part[tid + 128];
}

extern "C" void kernel_launch(void* const* d_in, const int* in_sizes, int n_in,
                              void* d_out, int out_size, void* d_ws, size_t ws_size,
                              hipStream_t stream){
  const float* node_feats = (const float*)d_in[0];
  const float* edge_feats = (const float*)d_in[1];
  const int*   src        = (const int*)  d_in[2];
  const int*   dst        = (const int*)  d_in[3];
  const float* W_ni       = (const float*)d_in[4];
  const float* W_nj       = (const float*)d_in[5];
  const float* W_fij      = (const float*)d_in[6];
  const float* W_node     = (const float*)d_in[7];
  const float* b_node     = (const float*)d_in[8];
  const float* attn       = (const float*)d_in[9];
  const float* bias_edge  = (const float*)d_in[10];
  const float* ek_c       = (const float*)d_in[11];
  const float* ek_b       = (const float*)d_in[12];
  const float* nk_c       = (const float*)d_in[13];
  const float* nk_b       = (const float*)d_in[14];
  const float* on_c       = (const float*)d_in[15];
  const float* on_b       = (const float*)d_in[16];
  const float* oe_c       = (const float*)d_in[17];
  const float* oe_b       = (const float*)d_in[18];

  const int N = in_sizes[0] / 128;
  const int E = in_sizes[2];

  float* ws = (float*)d_ws;
  size_t o = 0;
  float* P      = ws + o; o += (size_t)N*256;
  float* scores = ws + o; o += (size_t)E*4;
  float* smax   = ws + o; o += (size_t)N*4;
  float* rssum  = ws + o; o += (size_t)N*4;
  float* agg    = ws + o; o += (size_t)N*64;
  float* mk     = ws + o; o += (size_t)N*192;
  float* h      = ws + o; o += (size_t)N*512;
  float* h_out  = ws + o; o += (size_t)N*128;
  o = (o + 7) & ~(size_t)7;
  ushort* Bni  = (ushort*)(ws + o); o += 8192;    // 16384 bf16
  ushort* Bnj  = (ushort*)(ws + o); o += 8192;
  ushort* Bfij = (ushort*)(ws + o); o += 4096;    // 8192
  ushort* BE   = (ushort*)(ws + o); o += 16384;   // 32768
  ushort* BN_  = (ushort*)(ws + o); o += 36864;   // 73728
  ushort* BW   = (ushort*)(ws + o); o += 49152;   // 98304
  ushort* BO   = (ushort*)(ws + o); o += 65536;   // 131072
  ushort* BOE  = (ushort*)(ws + o); o += 4096;    // 8192
  int* deg    = (int*)(ws + o); o += N;
  int* cursor = (int*)(ws + o); o += N;
  int* off    = (int*)(ws + o); o += (size_t)(N + 1);
  int* eids   = (int*)(ws + o); o += E;

  float* out_node = (float*)d_out;
  float* out_edge = (float*)d_out + (size_t)N*128;

  (void)hipMemsetAsync(deg, 0, sizeof(int)*(size_t)(2*N), stream);   // deg + cursor

  k_deg <<<(E + 255)/256, 256, 0, stream>>>(dst, deg, E);
  k_scan<<<1, 1024, 0, stream>>>(deg, off, N);
  k_fill<<<(E + 255)/256, 256, 0, stream>>>(dst, off, cursor, eids, E);
  k_prep2<<<1505, 256, 0, stream>>>(W_ni, W_nj, W_fij, W_node, ek_c, nk_c, on_c, oe_c,
                                    Bni, Bnj, Bfij, BE, BN_, BW, BO, BOE);

  const int MB = (N + 63)/64;   // 782
  // P halves: node_feats @ W_ni / W_nj
  k_mm<0><<<dim3(MB, 2), 256, 0, stream>>>(node_feats, 128, nullptr, Bni, P,       256, nullptr, N, 128);
  k_mm<0><<<dim3(MB, 2), 256, 0, stream>>>(node_feats, 128, nullptr, Bnj, P + 128, 256, nullptr, N, 128);

  k_edge<<<E/32, 256, 0, stream>>>(P, edge_feats, src, dst, Bfij, BE, BOE,
                                   ek_b, bias_edge, attn, oe_b, scores, out_edge, E);

  k_nodestats<<<(N + 3)/4, 256, 0, stream>>>(edge_feats, scores, off, eids, agg, smax, rssum, N);

  // mk = kan_nk(concat(node_feats, agg)) ; h = mk @ W_node + b_node
  k_mm<2><<<dim3(MB, 3), 256, 0, stream>>>(node_feats, 128, agg, BN_, mk, 192, nk_b, N, 384);
  k_mm<0><<<dim3(MB, 8), 256, 0, stream>>>(mk, 192, nullptr, BW, h, 512, b_node, N, 192);

  k_aggr<<<N, 256, 0, stream>>>(h, scores, src, off, eids, smax, rssum, h_out, N);

  // out_node = kan_on(h_out)
  k_mm<1><<<dim3(MB, 2), 256, 0, stream>>>(h_out, 128, nullptr, BO, out_node, 128, on_b, N, 1024);
}